// Round 9
// baseline (137.471 us; speedup 1.0000x reference)
//
#include <hip/hip_runtime.h>
#include <stdint.h>

// OSTL spiking-LIF forward.
// R8: (1) GEMM k-loop unroll 8->4 (cap transient ds_read VGPRs ~64; suspected
//     scratch spill at unroll 8 with 64 acc regs). (2) reduce8 merged into the
//     scan (bitwise-identical pairwise tree per timestep, TB=8 raw double
//     buffer) - one fewer dispatch, 4 MB less traffic. (3) scan step chain
//     24->20 cyc via two-path select (values bit-identical).
// GEMM: split-K=8, 128x128 tile, 8x8 per-thread regs, 1 B/MAC LDS traffic.

#define T_STEPS 512
#define IN_SZ   1024
#define OUT_SZ  1024

#define BM 128
#define BN 128
#define BK 32
#define KSPLIT 8
#define KCHUNK (IN_SZ / KSPLIT)    // 128
#define NITER  (KCHUNK / BK)       // 4

typedef __attribute__((address_space(1))) const void gvoid;
typedef __attribute__((address_space(3))) void lvoid;

__global__ __launch_bounds__(256) void ostl_gemm_splitk(const float* __restrict__ X,
                                                        const float* __restrict__ W,
                                                        float* __restrict__ P) {
    __shared__ float As[2][BK][BM];     // A transposed [k][m]; reads broadcast, writes 2-way (free)
    __shared__ float Bs[2][BK * BN];    // linear [k][n]; filled by global_load_lds

    const int tid = threadIdx.x;
    const int tx = tid & 15;            // output cols tx*4..+3 and +64..+67
    const int ty = tid >> 4;            // output rows ty*8..+7
    const int n0 = blockIdx.x * BN;
    const int m0 = blockIdx.y * BM;
    const int kc = blockIdx.z;
    const int kb = kc * KCHUNK;

    const int am = tid >> 1;            // A row staged by this thread (0..127)
    const int ak = (tid & 1) * 16;      // A k-offset (0 or 16)
    const int wv = tid >> 6;            // wave 0..3
    const int ln = tid & 63;            // lane

    const float* Arow = X + (size_t)(m0 + am) * IN_SZ + kb + ak;

    float4 areg[4];

    // ---- prologue: tile 0 -> buffer 0 ----
    #pragma unroll
    for (int q = 0; q < 4; ++q)
        areg[q] = *reinterpret_cast<const float4*>(Arow + q * 4);
    #pragma unroll
    for (int j = 0; j < 4; ++j) {
        const int i = wv * 4 + j;
        const float* src = W + (size_t)(kb + 2 * i + (ln >> 5)) * OUT_SZ + n0 + (ln & 31) * 4;
        __builtin_amdgcn_global_load_lds((gvoid*)src, (lvoid*)&Bs[0][i * 256], 16, 0, 0);
    }
    {
        float t[16];
        #pragma unroll
        for (int q = 0; q < 4; ++q) *reinterpret_cast<float4*>(&t[q * 4]) = areg[q];
        #pragma unroll
        for (int c = 0; c < 16; ++c) As[0][ak + c][am] = t[c];
    }
    __syncthreads();

    float acc[8][8];
    #pragma unroll
    for (int r = 0; r < 8; ++r)
        #pragma unroll
        for (int c = 0; c < 8; ++c) acc[r][c] = 0.f;

    #pragma unroll 1
    for (int it = 0; it < NITER; ++it) {
        const int cur = it & 1;
        const int nxt = cur ^ 1;

        if (it < NITER - 1) {
            const int kbase = kb + (it + 1) * BK;
            #pragma unroll
            for (int j = 0; j < 4; ++j) {
                const int i = wv * 4 + j;
                const float* src = W + (size_t)(kbase + 2 * i + (ln >> 5)) * OUT_SZ + n0 + (ln & 31) * 4;
                __builtin_amdgcn_global_load_lds((gvoid*)src, (lvoid*)&Bs[nxt][i * 256], 16, 0, 0);
            }
            #pragma unroll
            for (int q = 0; q < 4; ++q)
                areg[q] = *reinterpret_cast<const float4*>(Arow + (it + 1) * BK + q * 4);
        }

        // 64 MACs per 64 LDS bytes per k-step (1 B/MAC).
        // unroll 4: <=16 in-flight ds_read_b128 (64 VGPR) + 64 acc = no spill.
        #pragma unroll 4
        for (int k = 0; k < BK; ++k) {
            const float4 a0 = *reinterpret_cast<const float4*>(&As[cur][k][ty * 8]);
            const float4 a1 = *reinterpret_cast<const float4*>(&As[cur][k][ty * 8 + 4]);
            const float4 b0 = *reinterpret_cast<const float4*>(&Bs[cur][k * BN + tx * 4]);
            const float4 b1 = *reinterpret_cast<const float4*>(&Bs[cur][k * BN + tx * 4 + 64]);
            const float av[8] = {a0.x, a0.y, a0.z, a0.w, a1.x, a1.y, a1.z, a1.w};
            const float bv[8] = {b0.x, b0.y, b0.z, b0.w, b1.x, b1.y, b1.z, b1.w};
            #pragma unroll
            for (int r = 0; r < 8; ++r)
                #pragma unroll
                for (int c = 0; c < 8; ++c)
                    acc[r][c] = fmaf(av[r], bv[c], acc[r][c]);
        }

        if (it < NITER - 1) {
            float t[16];
            #pragma unroll
            for (int q = 0; q < 4; ++q) *reinterpret_cast<float4*>(&t[q * 4]) = areg[q];
            #pragma unroll
            for (int c = 0; c < 16; ++c) As[nxt][ak + c][am] = t[c];
            __syncthreads();
        }
    }

    float* Pb = P + (size_t)kc * T_STEPS * OUT_SZ + (size_t)(m0 + ty * 8) * OUT_SZ + n0;
    #pragma unroll
    for (int r = 0; r < 8; ++r) {
        *reinterpret_cast<float4*>(&Pb[(size_t)r * OUT_SZ + tx * 4]) =
            make_float4(acc[r][0], acc[r][1], acc[r][2], acc[r][3]);
        *reinterpret_cast<float4*>(&Pb[(size_t)r * OUT_SZ + tx * 4 + 64]) =
            make_float4(acc[r][4], acc[r][5], acc[r][6], acc[r][7]);
    }
}

#define TB 8   // scan timestep block (raw-load double-buffered)

// Fused reduce+scan: per timestep, sum the 8 k-chunk partials with the SAME
// pairwise tree the old reduce8 used (bitwise identical), then the f64 LIF
// recurrence (two-path select form, values bit-identical to R7).
__global__ __launch_bounds__(64) void ostl_scan_fused(const float* __restrict__ u0,
                                                      const float* __restrict__ P,
                                                      float* __restrict__ Sout,
                                                      float* __restrict__ u_final) {
    const int j = blockIdx.x * 64 + threadIdx.x;
    const size_t CS = (size_t)T_STEPS * OUT_SZ;   // chunk stride in P

    const float  sig_f   = (float)0.8807970779778823;
    const double sig_tau = (double)sig_f;

    double u = (double)u0[j];
    const float* p = P + j;
    float* pout = Sout + j;

    float rawA[TB][8], rawB[TB][8];

    #pragma unroll
    for (int i = 0; i < TB; ++i)
        #pragma unroll
        for (int c = 0; c < 8; ++c)
            rawA[i][c] = p[c * CS + (size_t)i * OUT_SZ];

    float yA[TB], yB[TB];
    #pragma unroll
    for (int i = 0; i < TB; ++i) {
        const float t0 = rawA[i][0] + rawA[i][1], t1 = rawA[i][2] + rawA[i][3];
        const float t2 = rawA[i][4] + rawA[i][5], t3 = rawA[i][6] + rawA[i][7];
        yA[i] = (t0 + t1) + (t2 + t3);
    }

    #pragma unroll 1
    for (int blk = 0; blk < T_STEPS / TB; blk += 2) {
        // issue raw loads for block blk+1 (hidden under compute of blk)
        #pragma unroll
        for (int i = 0; i < TB; ++i)
            #pragma unroll
            for (int c = 0; c < 8; ++c)
                rawB[i][c] = p[c * CS + (size_t)((blk + 1) * TB + i) * OUT_SZ];

        #pragma unroll
        for (int i = 0; i < TB; ++i) {
            const double un = fma(sig_tau, u, (double)yA[i]);
            const double us = un - 1.0;
            const bool   sp = un > 1.0;
            pout[(size_t)(blk * TB + i) * OUT_SZ] = sp ? 1.0f : 0.0f;
            u = sp ? us : un;
        }

        #pragma unroll
        for (int i = 0; i < TB; ++i) {
            const float t0 = rawB[i][0] + rawB[i][1], t1 = rawB[i][2] + rawB[i][3];
            const float t2 = rawB[i][4] + rawB[i][5], t3 = rawB[i][6] + rawB[i][7];
            yB[i] = (t0 + t1) + (t2 + t3);
        }

        if (blk + 2 < T_STEPS / TB) {
            #pragma unroll
            for (int i = 0; i < TB; ++i)
                #pragma unroll
                for (int c = 0; c < 8; ++c)
                    rawA[i][c] = p[c * CS + (size_t)((blk + 2) * TB + i) * OUT_SZ];
        }

        #pragma unroll
        for (int i = 0; i < TB; ++i) {
            const double un = fma(sig_tau, u, (double)yB[i]);
            const double us = un - 1.0;
            const bool   sp = un > 1.0;
            pout[(size_t)((blk + 1) * TB + i) * OUT_SZ] = sp ? 1.0f : 0.0f;
            u = sp ? us : un;
        }

        if (blk + 2 < T_STEPS / TB) {
            #pragma unroll
            for (int i = 0; i < TB; ++i) {
                const float t0 = rawA[i][0] + rawA[i][1], t1 = rawA[i][2] + rawA[i][3];
                const float t2 = rawA[i][4] + rawA[i][5], t3 = rawA[i][6] + rawA[i][7];
                yA[i] = (t0 + t1) + (t2 + t3);
            }
        }
    }
    u_final[j] = (float)u;
}

extern "C" void kernel_launch(void* const* d_in, const int* in_sizes, int n_in,
                              void* d_out, int out_size, void* d_ws, size_t ws_size,
                              hipStream_t stream) {
    const float* x_seq  = (const float*)d_in[0];   // [512,1024]
    const float* kernel = (const float*)d_in[1];   // [1024,1024]
    const float* u0     = (const float*)d_in[2];   // [1024]
    // d_in[3] = E0: unused in the primal path.

    float* out      = (float*)d_out;
    float* spikes   = out;                               // [512,1024]
    float* u_final  = out + (size_t)T_STEPS * OUT_SZ;    // [1024]

    float* partials = (float*)d_ws;                      // 8 x [512,1024] = 16 MB

    dim3 ggrid(OUT_SZ / BN, T_STEPS / BM, KSPLIT);       // (8, 4, 8) = 256 blocks
    ostl_gemm_splitk<<<ggrid, dim3(256), 0, stream>>>(x_seq, kernel, partials);

    ostl_scan_fused<<<dim3(OUT_SZ / 64), dim3(64), 0, stream>>>(u0, partials, spikes, u_final);
}

// Round 11
// 115.486 us; speedup vs baseline: 1.1904x; 1.1904x over previous
//
#include <hip/hip_runtime.h>
#include <stdint.h>

// OSTL spiking-LIF forward.
// R10: revert to R7's measured GEMM (split-K=8, unroll-8) + parallel reduce8;
//   scan rebuilt as ONE WAVE PER COLUMN (1024 blocks x 64 lanes): lane l
//   preloads y[q*64+l] (8 independent loads, all in flight), recurrence runs
//   replicated on all lanes fed by compile-time-lane __shfl broadcasts that
//   sit OFF the f64 chain -> ~16cy/step. R8/R9 lesson: the fused scan starved
//   (16 waves, 8x traffic, 52.6us); parallelism, not fusion, is the fix.
// Numerics bit-identical to R7/R9-passing: same pairwise tree, same two-path
// select recurrence.

#define T_STEPS 512
#define IN_SZ   1024
#define OUT_SZ  1024

#define BM 128
#define BN 128
#define BK 32
#define KSPLIT 8
#define KCHUNK (IN_SZ / KSPLIT)    // 128
#define NITER  (KCHUNK / BK)       // 4

typedef __attribute__((address_space(1))) const void gvoid;
typedef __attribute__((address_space(3))) void lvoid;

__global__ __launch_bounds__(256) void ostl_gemm_splitk(const float* __restrict__ X,
                                                        const float* __restrict__ W,
                                                        float* __restrict__ P) {
    __shared__ float As[2][BK][BM];     // A transposed [k][m]; reads broadcast, writes 2-way (free)
    __shared__ float Bs[2][BK * BN];    // linear [k][n]; filled by global_load_lds

    const int tid = threadIdx.x;
    const int tx = tid & 15;            // output cols tx*4..+3 and +64..+67
    const int ty = tid >> 4;            // output rows ty*8..+7
    const int n0 = blockIdx.x * BN;
    const int m0 = blockIdx.y * BM;
    const int kc = blockIdx.z;
    const int kb = kc * KCHUNK;

    const int am = tid >> 1;            // A row staged by this thread (0..127)
    const int ak = (tid & 1) * 16;      // A k-offset (0 or 16)
    const int wv = tid >> 6;            // wave 0..3
    const int ln = tid & 63;            // lane

    const float* Arow = X + (size_t)(m0 + am) * IN_SZ + kb + ak;

    float4 areg[4];

    // ---- prologue: tile 0 -> buffer 0 ----
    #pragma unroll
    for (int q = 0; q < 4; ++q)
        areg[q] = *reinterpret_cast<const float4*>(Arow + q * 4);
    #pragma unroll
    for (int j = 0; j < 4; ++j) {
        const int i = wv * 4 + j;
        const float* src = W + (size_t)(kb + 2 * i + (ln >> 5)) * OUT_SZ + n0 + (ln & 31) * 4;
        __builtin_amdgcn_global_load_lds((gvoid*)src, (lvoid*)&Bs[0][i * 256], 16, 0, 0);
    }
    {
        float t[16];
        #pragma unroll
        for (int q = 0; q < 4; ++q) *reinterpret_cast<float4*>(&t[q * 4]) = areg[q];
        #pragma unroll
        for (int c = 0; c < 16; ++c) As[0][ak + c][am] = t[c];
    }
    __syncthreads();

    float acc[8][8];
    #pragma unroll
    for (int r = 0; r < 8; ++r)
        #pragma unroll
        for (int c = 0; c < 8; ++c) acc[r][c] = 0.f;

    #pragma unroll 1
    for (int it = 0; it < NITER; ++it) {
        const int cur = it & 1;
        const int nxt = cur ^ 1;

        if (it < NITER - 1) {
            const int kbase = kb + (it + 1) * BK;
            #pragma unroll
            for (int j = 0; j < 4; ++j) {
                const int i = wv * 4 + j;
                const float* src = W + (size_t)(kbase + 2 * i + (ln >> 5)) * OUT_SZ + n0 + (ln & 31) * 4;
                __builtin_amdgcn_global_load_lds((gvoid*)src, (lvoid*)&Bs[nxt][i * 256], 16, 0, 0);
            }
            #pragma unroll
            for (int q = 0; q < 4; ++q)
                areg[q] = *reinterpret_cast<const float4*>(Arow + (it + 1) * BK + q * 4);
        }

        // 64 MACs per 64 LDS bytes per k-step (1 B/MAC)
        #pragma unroll 8
        for (int k = 0; k < BK; ++k) {
            const float4 a0 = *reinterpret_cast<const float4*>(&As[cur][k][ty * 8]);
            const float4 a1 = *reinterpret_cast<const float4*>(&As[cur][k][ty * 8 + 4]);
            const float4 b0 = *reinterpret_cast<const float4*>(&Bs[cur][k * BN + tx * 4]);
            const float4 b1 = *reinterpret_cast<const float4*>(&Bs[cur][k * BN + tx * 4 + 64]);
            const float av[8] = {a0.x, a0.y, a0.z, a0.w, a1.x, a1.y, a1.z, a1.w};
            const float bv[8] = {b0.x, b0.y, b0.z, b0.w, b1.x, b1.y, b1.z, b1.w};
            #pragma unroll
            for (int r = 0; r < 8; ++r)
                #pragma unroll
                for (int c = 0; c < 8; ++c)
                    acc[r][c] = fmaf(av[r], bv[c], acc[r][c]);
        }

        if (it < NITER - 1) {
            float t[16];
            #pragma unroll
            for (int q = 0; q < 4; ++q) *reinterpret_cast<float4*>(&t[q * 4]) = areg[q];
            #pragma unroll
            for (int c = 0; c < 16; ++c) As[nxt][ak + c][am] = t[c];
            __syncthreads();
        }
    }

    float* Pb = P + (size_t)kc * T_STEPS * OUT_SZ + (size_t)(m0 + ty * 8) * OUT_SZ + n0;
    #pragma unroll
    for (int r = 0; r < 8; ++r) {
        *reinterpret_cast<float4*>(&Pb[(size_t)r * OUT_SZ + tx * 4]) =
            make_float4(acc[r][0], acc[r][1], acc[r][2], acc[r][3]);
        *reinterpret_cast<float4*>(&Pb[(size_t)r * OUT_SZ + tx * 4 + 64]) =
            make_float4(acc[r][4], acc[r][5], acc[r][6], acc[r][7]);
    }
}

__device__ inline float4 f4add(float4 a, float4 b) {
    return make_float4(a.x + b.x, a.y + b.y, a.z + b.z, a.w + b.w);
}

// deterministic pairwise tree over the 8 k-chunk partials (exact R6/R7 kernel)
__global__ __launch_bounds__(256) void ostl_reduce8(const float* __restrict__ P,
                                                    float* __restrict__ Y) {
    const size_t idx = ((size_t)blockIdx.x * 256 + threadIdx.x) * 4;
    float4 s[8];
    #pragma unroll
    for (int c = 0; c < 8; ++c)
        s[c] = *reinterpret_cast<const float4*>(P + (size_t)c * T_STEPS * OUT_SZ + idx);
    const float4 t0 = f4add(s[0], s[1]);
    const float4 t1 = f4add(s[2], s[3]);
    const float4 t2 = f4add(s[4], s[5]);
    const float4 t3 = f4add(s[6], s[7]);
    *reinterpret_cast<float4*>(Y + idx) = f4add(f4add(t0, t1), f4add(t2, t3));
}

// One wave per column: lane l holds y[t] for t = q*64+l (8 upfront loads,
// all independent -> full MLP). Recurrence replicated on all 64 lanes, fed by
// compile-time-lane __shfl broadcasts (off the f64 dependency chain).
// Lane l records spikes for its own t's (predicated) and writes them back.
__global__ __launch_bounds__(64) void ostl_scan_wave(const float* __restrict__ u0,
                                                     const float* __restrict__ Y,
                                                     float* __restrict__ Sout,
                                                     float* __restrict__ u_final) {
    const int j = blockIdx.x;       // column
    const int l = threadIdx.x;      // lane

    // Same constants/precision as the R7/R9-passing scan (bit-identical).
    const float  sig_f   = (float)0.8807970779778823;
    const double sig_tau = (double)sig_f;

    float y[8];
    #pragma unroll
    for (int q = 0; q < 8; ++q)
        y[q] = Y[(size_t)(q * 64 + l) * OUT_SZ + j];

    double u = (double)u0[j];
    float spk[8];

    #pragma unroll
    for (int q = 0; q < 8; ++q) {
        #pragma unroll
        for (int i = 0; i < 64; ++i) {
            const float  yv = __shfl(y[q], i, 64);      // compile-time lane
            const double un = fma(sig_tau, u, (double)yv);
            const double us = un - 1.0;
            const bool   sp = un > 1.0;
            const float  s  = sp ? 1.0f : 0.0f;
            if (i == l) spk[q] = s;                     // predicated, off-chain
            u = sp ? us : un;
        }
    }

    #pragma unroll
    for (int q = 0; q < 8; ++q)
        Sout[(size_t)(q * 64 + l) * OUT_SZ + j] = spk[q];
    if (l == 0) u_final[j] = (float)u;
}

extern "C" void kernel_launch(void* const* d_in, const int* in_sizes, int n_in,
                              void* d_out, int out_size, void* d_ws, size_t ws_size,
                              hipStream_t stream) {
    const float* x_seq  = (const float*)d_in[0];   // [512,1024]
    const float* kernel = (const float*)d_in[1];   // [1024,1024]
    const float* u0     = (const float*)d_in[2];   // [1024]
    // d_in[3] = E0: unused in the primal path.

    float* out      = (float*)d_out;
    float* spikes   = out;                               // [512,1024]
    float* u_final  = out + (size_t)T_STEPS * OUT_SZ;    // [1024]

    float* partials = (float*)d_ws;                      // 8 x [512,1024] = 16 MB
    float* yb       = partials + (size_t)KSPLIT * T_STEPS * OUT_SZ;  // [512,1024] = 2 MB

    dim3 ggrid(OUT_SZ / BN, T_STEPS / BM, KSPLIT);       // (8, 4, 8) = 256 blocks
    ostl_gemm_splitk<<<ggrid, dim3(256), 0, stream>>>(x_seq, kernel, partials);

    ostl_reduce8<<<dim3((T_STEPS * OUT_SZ / 4) / 256), dim3(256), 0, stream>>>(partials, yb);

    ostl_scan_wave<<<dim3(OUT_SZ), dim3(64), 0, stream>>>(u0, yb, spikes, u_final);
}

// Round 12
// 107.599 us; speedup vs baseline: 1.2776x; 1.0733x over previous
//
#include <hip/hip_runtime.h>
#include <stdint.h>

// OSTL spiking-LIF forward.
// R12: scan rebuilt (ONLY changed variable vs R11; gemm/reduce8 identical):
//   wave-per-column + v_readlane broadcast (SALU, no ds_bpermute), true q-loop
//   (5KB code, fits I$; R11's 40KB unrolled body streamed the 32KB I$), and
//   ZERO in-loop stores: spikes packed to bits (1 u32/lane), expanded to
//   floats by a parallel kernel. Tests: I$-streaming / bpermute-latency /
//   store-drain theories of the invariant ~50us scan.
// Numerics bit-identical to R7/R11-passing trajectory.

#define T_STEPS 512
#define IN_SZ   1024
#define OUT_SZ  1024

#define BM 128
#define BN 128
#define BK 32
#define KSPLIT 8
#define KCHUNK (IN_SZ / KSPLIT)    // 128
#define NITER  (KCHUNK / BK)       // 4

typedef __attribute__((address_space(1))) const void gvoid;
typedef __attribute__((address_space(3))) void lvoid;

__global__ __launch_bounds__(256) void ostl_gemm_splitk(const float* __restrict__ X,
                                                        const float* __restrict__ W,
                                                        float* __restrict__ P) {
    __shared__ float As[2][BK][BM];     // A transposed [k][m]; reads broadcast, writes 2-way (free)
    __shared__ float Bs[2][BK * BN];    // linear [k][n]; filled by global_load_lds

    const int tid = threadIdx.x;
    const int tx = tid & 15;            // output cols tx*4..+3 and +64..+67
    const int ty = tid >> 4;            // output rows ty*8..+7
    const int n0 = blockIdx.x * BN;
    const int m0 = blockIdx.y * BM;
    const int kc = blockIdx.z;
    const int kb = kc * KCHUNK;

    const int am = tid >> 1;            // A row staged by this thread (0..127)
    const int ak = (tid & 1) * 16;      // A k-offset (0 or 16)
    const int wv = tid >> 6;            // wave 0..3
    const int ln = tid & 63;            // lane

    const float* Arow = X + (size_t)(m0 + am) * IN_SZ + kb + ak;

    float4 areg[4];

    // ---- prologue: tile 0 -> buffer 0 ----
    #pragma unroll
    for (int q = 0; q < 4; ++q)
        areg[q] = *reinterpret_cast<const float4*>(Arow + q * 4);
    #pragma unroll
    for (int j = 0; j < 4; ++j) {
        const int i = wv * 4 + j;
        const float* src = W + (size_t)(kb + 2 * i + (ln >> 5)) * OUT_SZ + n0 + (ln & 31) * 4;
        __builtin_amdgcn_global_load_lds((gvoid*)src, (lvoid*)&Bs[0][i * 256], 16, 0, 0);
    }
    {
        float t[16];
        #pragma unroll
        for (int q = 0; q < 4; ++q) *reinterpret_cast<float4*>(&t[q * 4]) = areg[q];
        #pragma unroll
        for (int c = 0; c < 16; ++c) As[0][ak + c][am] = t[c];
    }
    __syncthreads();

    float acc[8][8];
    #pragma unroll
    for (int r = 0; r < 8; ++r)
        #pragma unroll
        for (int c = 0; c < 8; ++c) acc[r][c] = 0.f;

    #pragma unroll 1
    for (int it = 0; it < NITER; ++it) {
        const int cur = it & 1;
        const int nxt = cur ^ 1;

        if (it < NITER - 1) {
            const int kbase = kb + (it + 1) * BK;
            #pragma unroll
            for (int j = 0; j < 4; ++j) {
                const int i = wv * 4 + j;
                const float* src = W + (size_t)(kbase + 2 * i + (ln >> 5)) * OUT_SZ + n0 + (ln & 31) * 4;
                __builtin_amdgcn_global_load_lds((gvoid*)src, (lvoid*)&Bs[nxt][i * 256], 16, 0, 0);
            }
            #pragma unroll
            for (int q = 0; q < 4; ++q)
                areg[q] = *reinterpret_cast<const float4*>(Arow + (it + 1) * BK + q * 4);
        }

        // 64 MACs per 64 LDS bytes per k-step (1 B/MAC)
        #pragma unroll 8
        for (int k = 0; k < BK; ++k) {
            const float4 a0 = *reinterpret_cast<const float4*>(&As[cur][k][ty * 8]);
            const float4 a1 = *reinterpret_cast<const float4*>(&As[cur][k][ty * 8 + 4]);
            const float4 b0 = *reinterpret_cast<const float4*>(&Bs[cur][k * BN + tx * 4]);
            const float4 b1 = *reinterpret_cast<const float4*>(&Bs[cur][k * BN + tx * 4 + 64]);
            const float av[8] = {a0.x, a0.y, a0.z, a0.w, a1.x, a1.y, a1.z, a1.w};
            const float bv[8] = {b0.x, b0.y, b0.z, b0.w, b1.x, b1.y, b1.z, b1.w};
            #pragma unroll
            for (int r = 0; r < 8; ++r)
                #pragma unroll
                for (int c = 0; c < 8; ++c)
                    acc[r][c] = fmaf(av[r], bv[c], acc[r][c]);
        }

        if (it < NITER - 1) {
            float t[16];
            #pragma unroll
            for (int q = 0; q < 4; ++q) *reinterpret_cast<float4*>(&t[q * 4]) = areg[q];
            #pragma unroll
            for (int c = 0; c < 16; ++c) As[nxt][ak + c][am] = t[c];
            __syncthreads();
        }
    }

    float* Pb = P + (size_t)kc * T_STEPS * OUT_SZ + (size_t)(m0 + ty * 8) * OUT_SZ + n0;
    #pragma unroll
    for (int r = 0; r < 8; ++r) {
        *reinterpret_cast<float4*>(&Pb[(size_t)r * OUT_SZ + tx * 4]) =
            make_float4(acc[r][0], acc[r][1], acc[r][2], acc[r][3]);
        *reinterpret_cast<float4*>(&Pb[(size_t)r * OUT_SZ + tx * 4 + 64]) =
            make_float4(acc[r][4], acc[r][5], acc[r][6], acc[r][7]);
    }
}

__device__ inline float4 f4add(float4 a, float4 b) {
    return make_float4(a.x + b.x, a.y + b.y, a.z + b.z, a.w + b.w);
}

// deterministic pairwise tree over the 8 k-chunk partials (exact R6/R7 kernel)
__global__ __launch_bounds__(256) void ostl_reduce8(const float* __restrict__ P,
                                                    float* __restrict__ Y) {
    const size_t idx = ((size_t)blockIdx.x * 256 + threadIdx.x) * 4;
    float4 s[8];
    #pragma unroll
    for (int c = 0; c < 8; ++c)
        s[c] = *reinterpret_cast<const float4*>(P + (size_t)c * T_STEPS * OUT_SZ + idx);
    const float4 t0 = f4add(s[0], s[1]);
    const float4 t1 = f4add(s[2], s[3]);
    const float4 t2 = f4add(s[4], s[5]);
    const float4 t3 = f4add(s[6], s[7]);
    *reinterpret_cast<float4*>(Y + idx) = f4add(f4add(t0, t1), f4add(t2, t3));
}

// Wave-per-column scan, v_readlane broadcast, bit-packed spikes.
// Lane l preloads y[q*64+l]; per q-block the 64-step chain consumes
// readlane(ycur, i) (SALU, off the f64 chain). Spike for step (q,i) is
// recorded by lane i as bit q of sbits. One coalesced u32 store per lane.
__global__ __launch_bounds__(64) void ostl_scan_rl(const float* __restrict__ u0,
                                                   const float* __restrict__ Y,
                                                   unsigned* __restrict__ Bits,
                                                   float* __restrict__ u_final) {
    const int j = blockIdx.x;       // column
    const int l = threadIdx.x;      // lane

    // Same constants/precision/op-order as the R7/R11-passing scan.
    const float  sig_f   = (float)0.8807970779778823;
    const double sig_tau = (double)sig_f;

    double u = (double)u0[j];
    unsigned sbits = 0u;

    float ycur = Y[(size_t)l * OUT_SZ + j];            // q = 0
    #pragma unroll 1
    for (int q = 0; q < 8; ++q) {
        float ynext = 0.f;
        if (q < 7)                                     // prefetch next q-block
            ynext = Y[(size_t)((q + 1) * 64 + l) * OUT_SZ + j];
        const unsigned qbit = 1u << q;
        #pragma unroll
        for (int i = 0; i < 64; ++i) {
            const float  yv = __int_as_float(
                __builtin_amdgcn_readlane(__float_as_int(ycur), i));
            const double un = fma(sig_tau, u, (double)yv);
            const double us = un - 1.0;
            const bool   sp = un > 1.0;
            sbits |= (i == l && sp) ? qbit : 0u;       // off-chain
            u = sp ? us : un;
        }
        ycur = ynext;
    }
    Bits[(size_t)j * 64 + l] = sbits;                  // coalesced per wave
    if (l == 0) u_final[j] = (float)u;
}

// Expand packed bits to float spikes. Block = one timestep t: coalesced
// float4 writes; bit reads hit the L2-resident 256KB Bits array.
__global__ __launch_bounds__(256) void ostl_expand(const unsigned* __restrict__ Bits,
                                                   float* __restrict__ S) {
    const int t = blockIdx.x;          // 0..511
    const int c = t & 63;
    const int q = t >> 6;
    const int j4 = threadIdx.x * 4;
    float4 v;
    v.x = (float)((Bits[(size_t)(j4 + 0) * 64 + c] >> q) & 1u);
    v.y = (float)((Bits[(size_t)(j4 + 1) * 64 + c] >> q) & 1u);
    v.z = (float)((Bits[(size_t)(j4 + 2) * 64 + c] >> q) & 1u);
    v.w = (float)((Bits[(size_t)(j4 + 3) * 64 + c] >> q) & 1u);
    *reinterpret_cast<float4*>(&S[(size_t)t * OUT_SZ + j4]) = v;
}

extern "C" void kernel_launch(void* const* d_in, const int* in_sizes, int n_in,
                              void* d_out, int out_size, void* d_ws, size_t ws_size,
                              hipStream_t stream) {
    const float* x_seq  = (const float*)d_in[0];   // [512,1024]
    const float* kernel = (const float*)d_in[1];   // [1024,1024]
    const float* u0     = (const float*)d_in[2];   // [1024]
    // d_in[3] = E0: unused in the primal path.

    float* out      = (float*)d_out;
    float* spikes   = out;                               // [512,1024]
    float* u_final  = out + (size_t)T_STEPS * OUT_SZ;    // [1024]

    float*    partials = (float*)d_ws;                   // 8 x [512,1024] = 16 MB
    float*    yb       = partials + (size_t)KSPLIT * T_STEPS * OUT_SZ;  // 2 MB
    unsigned* bits     = (unsigned*)(yb + (size_t)T_STEPS * OUT_SZ);    // 256 KB

    dim3 ggrid(OUT_SZ / BN, T_STEPS / BM, KSPLIT);       // (8, 4, 8) = 256 blocks
    ostl_gemm_splitk<<<ggrid, dim3(256), 0, stream>>>(x_seq, kernel, partials);

    ostl_reduce8<<<dim3((T_STEPS * OUT_SZ / 4) / 256), dim3(256), 0, stream>>>(partials, yb);

    ostl_scan_rl<<<dim3(OUT_SZ), dim3(64), 0, stream>>>(u0, yb, bits, u_final);

    ostl_expand<<<dim3(T_STEPS), dim3(256), 0, stream>>>(bits, spikes);
}

// Round 13
// 106.933 us; speedup vs baseline: 1.2856x; 1.0062x over previous
//
#include <hip/hip_runtime.h>
#include <stdint.h>

// OSTL spiking-LIF forward.
// R13: ONE variable vs R12: scan recurrence f64 -> f32 (fmaf + two-path
//   select). Cross-round elimination showed every scan variant costs
//   ~150-225 cyc/step regardless of data movement (R5 prefetch == R2 naive;
//   R12 readlane/no-stores still ~33us) -> the common denominator is the f64
//   dependent chain. f32 chain: fma(6)+cmp(4)+cndmask(4) ~ 14 cyc/step.
//   Risk declared: f32 u deviates ~5e-7 (leak-damped) from the passing
//   f64-true trajectory; same error ball as np-vs-jax.
// gemm (split-K=8, unroll-8), reduce8, bit-pack + expand: identical to R12.

#define T_STEPS 512
#define IN_SZ   1024
#define OUT_SZ  1024

#define BM 128
#define BN 128
#define BK 32
#define KSPLIT 8
#define KCHUNK (IN_SZ / KSPLIT)    // 128
#define NITER  (KCHUNK / BK)       // 4

typedef __attribute__((address_space(1))) const void gvoid;
typedef __attribute__((address_space(3))) void lvoid;

__global__ __launch_bounds__(256) void ostl_gemm_splitk(const float* __restrict__ X,
                                                        const float* __restrict__ W,
                                                        float* __restrict__ P) {
    __shared__ float As[2][BK][BM];     // A transposed [k][m]; reads broadcast, writes 2-way (free)
    __shared__ float Bs[2][BK * BN];    // linear [k][n]; filled by global_load_lds

    const int tid = threadIdx.x;
    const int tx = tid & 15;            // output cols tx*4..+3 and +64..+67
    const int ty = tid >> 4;            // output rows ty*8..+7
    const int n0 = blockIdx.x * BN;
    const int m0 = blockIdx.y * BM;
    const int kc = blockIdx.z;
    const int kb = kc * KCHUNK;

    const int am = tid >> 1;            // A row staged by this thread (0..127)
    const int ak = (tid & 1) * 16;      // A k-offset (0 or 16)
    const int wv = tid >> 6;            // wave 0..3
    const int ln = tid & 63;            // lane

    const float* Arow = X + (size_t)(m0 + am) * IN_SZ + kb + ak;

    float4 areg[4];

    // ---- prologue: tile 0 -> buffer 0 ----
    #pragma unroll
    for (int q = 0; q < 4; ++q)
        areg[q] = *reinterpret_cast<const float4*>(Arow + q * 4);
    #pragma unroll
    for (int j = 0; j < 4; ++j) {
        const int i = wv * 4 + j;
        const float* src = W + (size_t)(kb + 2 * i + (ln >> 5)) * OUT_SZ + n0 + (ln & 31) * 4;
        __builtin_amdgcn_global_load_lds((gvoid*)src, (lvoid*)&Bs[0][i * 256], 16, 0, 0);
    }
    {
        float t[16];
        #pragma unroll
        for (int q = 0; q < 4; ++q) *reinterpret_cast<float4*>(&t[q * 4]) = areg[q];
        #pragma unroll
        for (int c = 0; c < 16; ++c) As[0][ak + c][am] = t[c];
    }
    __syncthreads();

    float acc[8][8];
    #pragma unroll
    for (int r = 0; r < 8; ++r)
        #pragma unroll
        for (int c = 0; c < 8; ++c) acc[r][c] = 0.f;

    #pragma unroll 1
    for (int it = 0; it < NITER; ++it) {
        const int cur = it & 1;
        const int nxt = cur ^ 1;

        if (it < NITER - 1) {
            const int kbase = kb + (it + 1) * BK;
            #pragma unroll
            for (int j = 0; j < 4; ++j) {
                const int i = wv * 4 + j;
                const float* src = W + (size_t)(kbase + 2 * i + (ln >> 5)) * OUT_SZ + n0 + (ln & 31) * 4;
                __builtin_amdgcn_global_load_lds((gvoid*)src, (lvoid*)&Bs[nxt][i * 256], 16, 0, 0);
            }
            #pragma unroll
            for (int q = 0; q < 4; ++q)
                areg[q] = *reinterpret_cast<const float4*>(Arow + (it + 1) * BK + q * 4);
        }

        // 64 MACs per 64 LDS bytes per k-step (1 B/MAC)
        #pragma unroll 8
        for (int k = 0; k < BK; ++k) {
            const float4 a0 = *reinterpret_cast<const float4*>(&As[cur][k][ty * 8]);
            const float4 a1 = *reinterpret_cast<const float4*>(&As[cur][k][ty * 8 + 4]);
            const float4 b0 = *reinterpret_cast<const float4*>(&Bs[cur][k * BN + tx * 4]);
            const float4 b1 = *reinterpret_cast<const float4*>(&Bs[cur][k * BN + tx * 4 + 64]);
            const float av[8] = {a0.x, a0.y, a0.z, a0.w, a1.x, a1.y, a1.z, a1.w};
            const float bv[8] = {b0.x, b0.y, b0.z, b0.w, b1.x, b1.y, b1.z, b1.w};
            #pragma unroll
            for (int r = 0; r < 8; ++r)
                #pragma unroll
                for (int c = 0; c < 8; ++c)
                    acc[r][c] = fmaf(av[r], bv[c], acc[r][c]);
        }

        if (it < NITER - 1) {
            float t[16];
            #pragma unroll
            for (int q = 0; q < 4; ++q) *reinterpret_cast<float4*>(&t[q * 4]) = areg[q];
            #pragma unroll
            for (int c = 0; c < 16; ++c) As[nxt][ak + c][am] = t[c];
            __syncthreads();
        }
    }

    float* Pb = P + (size_t)kc * T_STEPS * OUT_SZ + (size_t)(m0 + ty * 8) * OUT_SZ + n0;
    #pragma unroll
    for (int r = 0; r < 8; ++r) {
        *reinterpret_cast<float4*>(&Pb[(size_t)r * OUT_SZ + tx * 4]) =
            make_float4(acc[r][0], acc[r][1], acc[r][2], acc[r][3]);
        *reinterpret_cast<float4*>(&Pb[(size_t)r * OUT_SZ + tx * 4 + 64]) =
            make_float4(acc[r][4], acc[r][5], acc[r][6], acc[r][7]);
    }
}

__device__ inline float4 f4add(float4 a, float4 b) {
    return make_float4(a.x + b.x, a.y + b.y, a.z + b.z, a.w + b.w);
}

// deterministic pairwise tree over the 8 k-chunk partials (exact R6/R7 kernel)
__global__ __launch_bounds__(256) void ostl_reduce8(const float* __restrict__ P,
                                                    float* __restrict__ Y) {
    const size_t idx = ((size_t)blockIdx.x * 256 + threadIdx.x) * 4;
    float4 s[8];
    #pragma unroll
    for (int c = 0; c < 8; ++c)
        s[c] = *reinterpret_cast<const float4*>(P + (size_t)c * T_STEPS * OUT_SZ + idx);
    const float4 t0 = f4add(s[0], s[1]);
    const float4 t1 = f4add(s[2], s[3]);
    const float4 t2 = f4add(s[4], s[5]);
    const float4 t3 = f4add(s[6], s[7]);
    *reinterpret_cast<float4*>(Y + idx) = f4add(f4add(t0, t1), f4add(t2, t3));
}

// Wave-per-column scan, v_readlane broadcast, bit-packed spikes, f32 chain.
__global__ __launch_bounds__(64) void ostl_scan_rl(const float* __restrict__ u0,
                                                   const float* __restrict__ Y,
                                                   unsigned* __restrict__ Bits,
                                                   float* __restrict__ u_final) {
    const int j = blockIdx.x;       // column
    const int l = threadIdx.x;      // lane

    const float sig_f = (float)0.8807970779778823;

    float u = u0[j];
    unsigned sbits = 0u;

    float ycur = Y[(size_t)l * OUT_SZ + j];            // q = 0
    #pragma unroll 1
    for (int q = 0; q < 8; ++q) {
        float ynext = 0.f;
        if (q < 7)                                     // prefetch next q-block
            ynext = Y[(size_t)((q + 1) * 64 + l) * OUT_SZ + j];
        const unsigned qbit = 1u << q;
        #pragma unroll
        for (int i = 0; i < 64; ++i) {
            const float yv = __int_as_float(
                __builtin_amdgcn_readlane(__float_as_int(ycur), i));
            const float un = fmaf(sig_f, u, yv);       // f32 chain: fma->cmp->cndmask
            const float us = un - 1.0f;
            const bool  sp = un > 1.0f;
            sbits |= (i == l && sp) ? qbit : 0u;       // off-chain
            u = sp ? us : un;
        }
        ycur = ynext;
    }
    Bits[(size_t)j * 64 + l] = sbits;                  // coalesced per wave
    if (l == 0) u_final[j] = u;
}

// Expand packed bits to float spikes. Block = one timestep t: coalesced
// float4 writes; bit reads hit the L2-resident 256KB Bits array.
__global__ __launch_bounds__(256) void ostl_expand(const unsigned* __restrict__ Bits,
                                                   float* __restrict__ S) {
    const int t = blockIdx.x;          // 0..511
    const int c = t & 63;
    const int q = t >> 6;
    const int j4 = threadIdx.x * 4;
    float4 v;
    v.x = (float)((Bits[(size_t)(j4 + 0) * 64 + c] >> q) & 1u);
    v.y = (float)((Bits[(size_t)(j4 + 1) * 64 + c] >> q) & 1u);
    v.z = (float)((Bits[(size_t)(j4 + 2) * 64 + c] >> q) & 1u);
    v.w = (float)((Bits[(size_t)(j4 + 3) * 64 + c] >> q) & 1u);
    *reinterpret_cast<float4*>(&S[(size_t)t * OUT_SZ + j4]) = v;
}

extern "C" void kernel_launch(void* const* d_in, const int* in_sizes, int n_in,
                              void* d_out, int out_size, void* d_ws, size_t ws_size,
                              hipStream_t stream) {
    const float* x_seq  = (const float*)d_in[0];   // [512,1024]
    const float* kernel = (const float*)d_in[1];   // [1024,1024]
    const float* u0     = (const float*)d_in[2];   // [1024]
    // d_in[3] = E0: unused in the primal path.

    float* out      = (float*)d_out;
    float* spikes   = out;                               // [512,1024]
    float* u_final  = out + (size_t)T_STEPS * OUT_SZ;    // [1024]

    float*    partials = (float*)d_ws;                   // 8 x [512,1024] = 16 MB
    float*    yb       = partials + (size_t)KSPLIT * T_STEPS * OUT_SZ;  // 2 MB
    unsigned* bits     = (unsigned*)(yb + (size_t)T_STEPS * OUT_SZ);    // 256 KB

    dim3 ggrid(OUT_SZ / BN, T_STEPS / BM, KSPLIT);       // (8, 4, 8) = 256 blocks
    ostl_gemm_splitk<<<ggrid, dim3(256), 0, stream>>>(x_seq, kernel, partials);

    ostl_reduce8<<<dim3((T_STEPS * OUT_SZ / 4) / 256), dim3(256), 0, stream>>>(partials, yb);

    ostl_scan_rl<<<dim3(OUT_SZ), dim3(64), 0, stream>>>(u0, yb, bits, u_final);

    ostl_expand<<<dim3(T_STEPS), dim3(256), 0, stream>>>(bits, spikes);
}